// Round 1
// baseline (251.258 us; speedup 1.0000x reference)
//
#include <hip/hip_runtime.h>

#define T_IN   1048576
#define T_OUT  1048564              // T_IN - 12 (valid 5-tap then valid 9-tap)
#define QPR    262141               // output float4 quads per row (T_OUT/4)
#define BPR    256                  // blocks per row: 256 blk * 256 thr * 4 quads = 262144 >= QPR
#define NROWS  32                   // 8 * 4 rows, conv is independent per row

// v2: no LDS, no barrier. Each thread produces 16 consecutive outputs
// (4 float4 quads) from 28 input floats fetched as 7 independent float4
// loads. Neighbor overlap (48 B/thread) is L1-served; HBM traffic stays
// ~1x read + 1x write. 13-tap compose amortized over 16 outputs.
__device__ __forceinline__ void compose13(const float* __restrict__ fd,
                                          const float* __restrict__ gs,
                                          float c[13])
{
    float f[5], g[9];
#pragma unroll
    for (int i = 0; i < 5; ++i) f[i] = fd[i];
#pragma unroll
    for (int j = 0; j < 9; ++j) g[j] = gs[j];
#pragma unroll
    for (int k = 0; k < 13; ++k) c[k] = 0.0f;
#pragma unroll
    for (int i = 0; i < 5; ++i)
#pragma unroll
        for (int j = 0; j < 9; ++j) c[i + j] = fmaf(f[i], g[j], c[i + j]);
}

__global__ __launch_bounds__(256) void pinn_fused_conv13_v2(
    const float* __restrict__ x,
    const float* __restrict__ fd,     // 5 taps (already scaled by 1/h^2)
    const float* __restrict__ gs,     // 9 taps
    float* __restrict__ out)
{
    const int r  = blockIdx.x >> 8;         // row 0..31
    const int b  = blockIdx.x & (BPR - 1);  // block-in-row
    const int t  = threadIdx.x;
    const int q0 = (b << 10) + (t << 2);    // first of this thread's 4 quads
    const int f0 = q0 << 2;                 // first input/output float index

    const float* __restrict__ xrow = x + (size_t)r * T_IN;
    float*       __restrict__ orow = out + (size_t)r * T_OUT;

    if (q0 + 3 < QPR) {
        // ---- fast path (all threads except 1 per row) ----
        // inputs [f0, f0+28): max f0 = 4*262136 -> last index 1048571 < T_IN. safe.
        float4 v[7];
#pragma unroll
        for (int i = 0; i < 7; ++i)
            v[i] = *reinterpret_cast<const float4*>(xrow + f0 + 4 * i);

        // compose while loads are in flight
        float c[13];
        compose13(fd, gs, c);

        float a[28];
#pragma unroll
        for (int i = 0; i < 7; ++i) {
            a[4 * i + 0] = v[i].x;
            a[4 * i + 1] = v[i].y;
            a[4 * i + 2] = v[i].z;
            a[4 * i + 3] = v[i].w;
        }

        float4 o[4];
        float* op = reinterpret_cast<float*>(o);
#pragma unroll
        for (int j = 0; j < 16; ++j) {
            float s = c[0] * a[j];
#pragma unroll
            for (int k = 1; k < 13; ++k) s = fmaf(c[k], a[j + k], s);
            op[j] = s;
        }
#pragma unroll
        for (int i = 0; i < 4; ++i)
            *reinterpret_cast<float4*>(orow + f0 + 4 * i) = o[i];
    } else {
        // ---- tail: only thread 255 of the last block in each row ----
        float c[13];
        compose13(fd, gs, c);
#pragma unroll
        for (int i = 0; i < 4; ++i) {
            const int q = q0 + i;
            if (q < QPR) {
                const float* p = xrow + (q << 2);   // inputs [4q, 4q+16) <= T_IN
                float a[16];
#pragma unroll
                for (int k = 0; k < 16; ++k) a[k] = p[k];
                float4 ov;
                float* op = &ov.x;
#pragma unroll
                for (int j = 0; j < 4; ++j) {
                    float s = c[0] * a[j];
#pragma unroll
                    for (int k = 1; k < 13; ++k) s = fmaf(c[k], a[j + k], s);
                    op[j] = s;
                }
                *reinterpret_cast<float4*>(orow + (q << 2)) = ov;
            }
        }
    }
}

extern "C" void kernel_launch(void* const* d_in, const int* in_sizes, int n_in,
                              void* d_out, int out_size, void* d_ws, size_t ws_size,
                              hipStream_t stream) {
    const float* x  = (const float*)d_in[0];
    const float* fd = (const float*)d_in[1];
    const float* gs = (const float*)d_in[2];
    float* out = (float*)d_out;

    // 32 rows x 256 blocks/row = 8192 blocks of 256 threads, 16 outputs/thread.
    pinn_fused_conv13_v2<<<NROWS * BPR, 256, 0, stream>>>(x, fd, gs, out);
}